// Round 13
// baseline (194.813 us; speedup 1.0000x reference)
//
#include <hip/hip_runtime.h>
#include <math.h>

#define DIM 64
#define KC 32
#define NPTS 32768
#define LOG_2PI 1.8378770664093453f
#define C0 (-58.0f)   // fixed logsumexp reference: logp <= -58.81 always
#define ST 68         // prep LDS row stride (words)
#define MAGIC 0x13579BDF

typedef __attribute__((ext_vector_type(8))) short short8;
typedef __attribute__((ext_vector_type(4))) float float4v;

__device__ __forceinline__ unsigned short f2bf(float f) {
    unsigned u = __float_as_uint(f);
    u += 0x7FFFu + ((u >> 16) & 1u);   // RNE
    return (unsigned short)(u >> 16);
}

__device__ __forceinline__ float rdlane(float v, int l) {
    return __int_as_float(__builtin_amdgcn_readlane(__float_as_int(v), l));
}

// DPP adds (VALU pipe) — HW-verified correct rounds 7-12.
template <int CTRL>
__device__ __forceinline__ float dpp_add(float x) {
    int t = __builtin_amdgcn_mov_dpp(__float_as_int(x), CTRL, 0xF, 0xF, true);
    return x + __int_as_float(t);
}
__device__ __forceinline__ float sum16(float x) {
    x = dpp_add<0xB1>(x);
    x = dpp_add<0x4E>(x);
    x = dpp_add<0x141>(x);
    x = dpp_add<0x140>(x);
    return x;
}

struct PrepSh {
    float Llds[DIM * ST];
    float Sig[DIM * ST];
    float Clds[DIM * ST];
    float Ylds[DIM * ST];   // Ylds[a*ST+b] = M[b][a]
    float qlds[DIM];
    float rdbuf[DIM];
    float ldet;
};
struct MainSh {
    float4 Bsh[3072];       // 48 KB
    float pm[4];
};
union SharedU { PrepSh p; MainSh m; };

// ============================================================================
// Single fused kernel: 2048 blocks x 256.
// Phase A (blocks 0..31): frozen r10/r12 prep for k = blockIdx (4-col blocked
//   two-wave Cholesky+inverse) -> Bpack slice + cstC[k]; threadfence;
//   atomicExch(flags[k], MAGIC). Block 0 zeroes tailctr BEFORE its flag.
// Phase B (all blocks): load A fragments (overlaps prep), spin on the 32
//   flags (lane i polls flags[i]; agent-scope acquire loads + s_sleep),
//   stage B to LDS, r12 main loop, r10-validated atomic tail reduction.
// No-deadlock: blocks 0..31 are in the first resident wave; later blocks
// only ever wait on flags that get set. Poison 0xAA != MAGIC, no init needed.
// ============================================================================
__global__ __launch_bounds__(256, 2) void fused_kernel(
    const float* __restrict__ X, const float* __restrict__ mu,
    const float* __restrict__ L, const float* __restrict__ w,
    short* __restrict__ Bpack, float* __restrict__ cstC,
    float* __restrict__ partials, int* __restrict__ flags,
    int* __restrict__ tailctr, float* __restrict__ out)
{
    const int bid = blockIdx.x;
    const int tid = threadIdx.x;
    const int lane = tid & 63;
    const int wv = tid >> 6;
    __shared__ SharedU sh;
    __shared__ int lastdone;

    if (bid == 0 && tid == 0) *tailctr = 0;   // before block 0's flag (ordering)

    // ======================= Phase A: prep (blocks 0..31) ===================
    if (bid < KC) {
        const int k = bid;
        const int t = tid;
        const int ln = lane;
        float* Llds = sh.p.Llds;
        float* Sig  = sh.p.Sig;
        float* Clds = sh.p.Clds;
        float* Ylds = sh.p.Ylds;

        for (int idx = t; idx < DIM * DIM; idx += 256) {
            int r = idx >> 6, c = idx & 63;
            float v = L[(size_t)k * DIM * DIM + idx];
            Llds[r * ST + c] = (c <= r) ? v : 0.f;
        }
        for (int idx = t; idx < DIM * ST; idx += 256) {
            Clds[idx] = 0.f;
            Ylds[idx] = 0.f;
        }
        __syncthreads();

        {
            float Lr[DIM];
            const float2* lp = (const float2*)(Llds + ln * ST);
#pragma unroll
            for (int p = 0; p < 32; ++p) {
                float2 v = lp[p];
                Lr[2 * p] = v.x; Lr[2 * p + 1] = v.y;
            }
#pragma unroll 1
            for (int jj = 0; jj < 16; ++jj) {
                const int j = wv * 16 + jj;
                const float2* up = (const float2*)(Llds + j * ST);
                float a0 = 0.f, a1 = 0.f, a2 = 0.f, a3 = 0.f;
#pragma unroll
                for (int p = 0; p < 32; p += 2) {
                    float2 u0 = up[p], u1 = up[p + 1];
                    a0 = fmaf(Lr[2 * p], u0.x, a0);
                    a1 = fmaf(Lr[2 * p + 1], u0.y, a1);
                    a2 = fmaf(Lr[2 * p + 2], u1.x, a2);
                    a3 = fmaf(Lr[2 * p + 3], u1.y, a3);
                }
                float s = (a0 + a1) + (a2 + a3);
                if (j == ln) s += 1.f;
                Sig[ln * ST + j] = s;
            }
        }
        __syncthreads();

        {
            const float2* crow = (const float2*)(Clds + ln * ST);
            const float2* yrow = (const float2*)(Ylds + ln * ST);
            float ld2 = 0.f;
#pragma unroll 1
            for (int c = 0; c < DIM; c += 4) {
                const float2* u0 = (const float2*)(Clds + (c + 0) * ST);
                const float2* u1 = (const float2*)(Clds + (c + 1) * ST);
                const float2* u2 = (const float2*)(Clds + (c + 2) * ST);
                const float2* u3 = (const float2*)(Clds + (c + 3) * ST);
                float si0 = 0.f, si1 = 0.f, si2 = 0.f, si3 = 0.f;
                if (wv == 0) {
                    float d0a = 0.f, d0b = 0.f, d1a = 0.f, d1b = 0.f;
                    float d2a = 0.f, d2b = 0.f, d3a = 0.f, d3b = 0.f;
#pragma unroll
                    for (int p = 0; p < 32; ++p) {
                        float2 cr = crow[p];
                        float2 a0 = u0[p], a1 = u1[p], a2 = u2[p], a3 = u3[p];
                        d0a = fmaf(cr.x, a0.x, d0a); d0b = fmaf(cr.y, a0.y, d0b);
                        d1a = fmaf(cr.x, a1.x, d1a); d1b = fmaf(cr.y, a1.y, d1b);
                        d2a = fmaf(cr.x, a2.x, d2a); d2b = fmaf(cr.y, a2.y, d2b);
                        d3a = fmaf(cr.x, a3.x, d3a); d3b = fmaf(cr.y, a3.y, d3b);
                    }
                    const float4 sg = *(const float4*)(Sig + ln * ST + c);
                    float s0 = sg.x - (d0a + d0b);
                    float s1 = sg.y - (d1a + d1b);
                    float s2 = sg.z - (d2a + d2b);
                    float s3 = sg.w - (d3a + d3b);
                    float dd0 = rdlane(s0, c + 0);
                    float rd0 = __builtin_amdgcn_rsqf(dd0);
                    float c0v = s0 * rd0;
                    s1 = fmaf(-c0v, rdlane(c0v, c + 1), s1);
                    s2 = fmaf(-c0v, rdlane(c0v, c + 2), s2);
                    s3 = fmaf(-c0v, rdlane(c0v, c + 3), s3);
                    float dd1 = rdlane(s1, c + 1);
                    float rd1 = __builtin_amdgcn_rsqf(dd1);
                    float c1v = s1 * rd1;
                    s2 = fmaf(-c1v, rdlane(c1v, c + 2), s2);
                    s3 = fmaf(-c1v, rdlane(c1v, c + 3), s3);
                    float dd2 = rdlane(s2, c + 2);
                    float rd2 = __builtin_amdgcn_rsqf(dd2);
                    float c2v = s2 * rd2;
                    s3 = fmaf(-c2v, rdlane(c2v, c + 3), s3);
                    float dd3 = rdlane(s3, c + 3);
                    float rd3 = __builtin_amdgcn_rsqf(dd3);
                    float c3v = s3 * rd3;
                    ld2 += (__logf(dd0) + __logf(dd1)) + (__logf(dd2) + __logf(dd3));
                    *(float4*)(Clds + ln * ST + c) = make_float4(c0v, c1v, c2v, c3v);
                    if (ln == 0) *(float4*)(sh.p.rdbuf + c) = make_float4(rd0, rd1, rd2, rd3);
                } else if (wv == 1) {
                    float e0a = 0.f, e0b = 0.f, e1a = 0.f, e1b = 0.f;
                    float e2a = 0.f, e2b = 0.f, e3a = 0.f, e3b = 0.f;
#pragma unroll
                    for (int p = 0; p < 32; ++p) {
                        float2 yr = yrow[p];
                        float2 a0 = u0[p], a1 = u1[p], a2 = u2[p], a3 = u3[p];
                        e0a = fmaf(yr.x, a0.x, e0a); e0b = fmaf(yr.y, a0.y, e0b);
                        e1a = fmaf(yr.x, a1.x, e1a); e1b = fmaf(yr.y, a1.y, e1b);
                        e2a = fmaf(yr.x, a2.x, e2a); e2b = fmaf(yr.y, a2.y, e2b);
                        e3a = fmaf(yr.x, a3.x, e3a); e3b = fmaf(yr.y, a3.y, e3b);
                    }
                    si0 = ((ln == c + 0) ? 1.f : 0.f) - (e0a + e0b);
                    si1 = ((ln == c + 1) ? 1.f : 0.f) - (e1a + e1b);
                    si2 = ((ln == c + 2) ? 1.f : 0.f) - (e2a + e2b);
                    si3 = ((ln == c + 3) ? 1.f : 0.f) - (e3a + e3b);
                }
                __syncthreads();
                if (wv == 1) {
                    const float4 rdv = *(const float4*)(sh.p.rdbuf + c);
                    float C10 = Clds[(c + 1) * ST + c];
                    float C20 = Clds[(c + 2) * ST + c];
                    float C21 = Clds[(c + 2) * ST + c + 1];
                    float C30 = Clds[(c + 3) * ST + c];
                    float C31 = Clds[(c + 3) * ST + c + 1];
                    float C32 = Clds[(c + 3) * ST + c + 2];
                    float y0 = si0 * rdv.x;
                    float y1 = (si1 - C10 * y0) * rdv.y;
                    float y2 = (si2 - C20 * y0 - C21 * y1) * rdv.z;
                    float y3 = (si3 - C30 * y0 - C31 * y1 - C32 * y2) * rdv.w;
                    float4 yo;
                    yo.x = (ln <= c + 0) ? y0 : 0.f;
                    yo.y = (ln <= c + 1) ? y1 : 0.f;
                    yo.z = (ln <= c + 2) ? y2 : 0.f;
                    yo.w = (ln <= c + 3) ? y3 : 0.f;
                    *(float4*)(Ylds + ln * ST + c) = yo;
                }
            }
            if (wv == 0 && ln == 0) sh.p.ldet = ld2;
        }
        __syncthreads();

        if (wv == 0) {
            const float* muk = mu + k * DIM;
            float qv = 0.f;
#pragma unroll 8
            for (int j = 0; j < DIM; ++j)
                qv = fmaf(Ylds[j * ST + ln], muk[j], qv);
            sh.p.qlds[ln] = qv;
            if (ln == 0) {
                float wm = -3.0e38f;
                for (int i = 0; i < KC; ++i) wm = fmaxf(wm, w[i]);
                float se = 0.f;
                for (int i = 0; i < KC; ++i) se += __expf(w[i] - wm);
                float logw = w[k] - (wm + __logf(se));
                cstC[k] = -0.5f * (DIM * LOG_2PI + sh.p.ldet) + logw - C0;
            }
        }
        __syncthreads();

        {
            const int ct = wv;
            const int col = ct * 16 + (ln & 15);
            const int kb = (ln >> 4) * 8;
#pragma unroll
            for (int kt = 0; kt < 3; ++kt) {
                short8 v;
                if (kt < 2) {
#pragma unroll
                    for (int e = 0; e < 8; ++e)
                        v[e] = (short)f2bf(Ylds[(kt * 32 + kb + e) * ST + col]);
                } else {
#pragma unroll
                    for (int e = 0; e < 8; ++e)
                        v[e] = (short)((kb + e == 0) ? f2bf(-sh.p.qlds[col]) : 0);
                }
                *(short8*)(Bpack + ((size_t)(k * 12 + ct * 3 + kt) * 64 + ln) * 8) = v;
            }
        }
        __threadfence();
        __syncthreads();
        if (tid == 0) atomicExch(&flags[k], MAGIC);   // release this k's slice
    }

    // ======================= Phase B: main (all blocks) =====================
    const int ks = bid & 7;                // k in [4ks, 4ks+4)
    const int g = bid >> 3;                // row group: 128 rows
    const int m = lane & 15;

    // A fragments first (independent of B -> overlaps with prep/spin)
    const int rbase = g * 128 + wv * 32;
    const int jb = (lane >> 4) * 8;
    const float* Xr0 = X + (size_t)(rbase + m) * DIM;
    const float* Xr1 = Xr0 + 16 * DIM;
    short8 a0, a1, b0r, b1r;
#pragma unroll
    for (int e = 0; e < 8; ++e) {
        a0[e] = (short)f2bf(Xr0[jb + e]);
        a1[e] = (short)f2bf(Xr0[32 + jb + e]);
        b0r[e] = (short)f2bf(Xr1[jb + e]);
        b1r[e] = (short)f2bf(Xr1[32 + jb + e]);
    }

    // Spin until all 32 Bpack slices are published (lane i polls flags[i])
    if (tid < KC) {
        while (__hip_atomic_load(&flags[tid], __ATOMIC_ACQUIRE,
                                 __HIP_MEMORY_SCOPE_AGENT) != MAGIC)
            __builtin_amdgcn_s_sleep(2);
    }
    __syncthreads();   // also separates prep-LDS use from Bsh reuse

    // Stage this block's B slice (48 KB) into LDS
    {
        const float4* Bg = (const float4*)Bpack + (size_t)ks * 3072;
#pragma unroll
        for (int it = 0; it < 12; ++it)
            sh.m.Bsh[it * 256 + tid] = Bg[it * 256 + tid];
    }
    __syncthreads();

    const short8* Bs = (const short8*)sh.m.Bsh;
    const short* Bss = (const short*)sh.m.Bsh;
    float acc = 0.f;
#pragma unroll
    for (int kk = 0; kk < 4; ++kk) {
        const int k = ks * 4 + kk;
        float p0 = 0.f, p1 = 0.f, p2 = 0.f, p3 = 0.f;
        float r0 = 0.f, r1 = 0.f, r2 = 0.f, r3 = 0.f;
#pragma unroll
        for (int ct = 0; ct < 4; ++ct) {
            short8 f0 = Bs[(kk * 12 + ct * 3 + 0) * 64 + lane];
            short8 f1 = Bs[(kk * 12 + ct * 3 + 1) * 64 + lane];
            short nqs = Bss[(size_t)((kk * 12 + ct * 3 + 2) * 64 + m) * 8];
            float nq = __int_as_float(((int)(unsigned short)nqs) << 16);
            float4v c0 = {nq, nq, nq, nq};   // -q folded via accumulator init
            c0 = __builtin_amdgcn_mfma_f32_16x16x32_bf16(a0, f0, c0, 0, 0, 0);
            c0 = __builtin_amdgcn_mfma_f32_16x16x32_bf16(a1, f1, c0, 0, 0, 0);
            float4v c1 = {nq, nq, nq, nq};
            c1 = __builtin_amdgcn_mfma_f32_16x16x32_bf16(b0r, f0, c1, 0, 0, 0);
            c1 = __builtin_amdgcn_mfma_f32_16x16x32_bf16(b1r, f1, c1, 0, 0, 0);
            p0 = fmaf(c0[0], c0[0], p0); p1 = fmaf(c0[1], c0[1], p1);
            p2 = fmaf(c0[2], c0[2], p2); p3 = fmaf(c0[3], c0[3], p3);
            r0 = fmaf(c1[0], c1[0], r0); r1 = fmaf(c1[1], c1[1], r1);
            r2 = fmaf(c1[2], c1[2], r2); r3 = fmaf(c1[3], c1[3], r3);
        }
        const float cc = cstC[k];
        acc += __expf(fmaf(-0.5f, sum16(p0), cc)) + __expf(fmaf(-0.5f, sum16(p1), cc));
        acc += __expf(fmaf(-0.5f, sum16(p2), cc)) + __expf(fmaf(-0.5f, sum16(p3), cc));
        acc += __expf(fmaf(-0.5f, sum16(r0), cc)) + __expf(fmaf(-0.5f, sum16(r1), cc));
        acc += __expf(fmaf(-0.5f, sum16(r2), cc)) + __expf(fmaf(-0.5f, sum16(r3), cc));
    }
    acc += __shfl_xor(acc, 16, 64);
    acc += __shfl_xor(acc, 32, 64);

    if (lane == 0) sh.m.pm[wv] = acc;
    __syncthreads();
    if (tid == 0) {
        partials[bid] = (sh.m.pm[0] + sh.m.pm[1]) + (sh.m.pm[2] + sh.m.pm[3]);
        __threadfence();
        lastdone = (atomicAdd(tailctr, 1) == 2047) ? 1 : 0;
    }
    __syncthreads();
    if (lastdone) {
        __threadfence();
        float s = 0.f;
        for (int i = tid; i < 2048; i += 256) s += partials[i];
#pragma unroll
        for (int mm = 1; mm <= 32; mm <<= 1) s += __shfl_xor(s, mm, 64);
        if (lane == 0) sh.m.pm[wv] = s;
        __syncthreads();
        if (tid == 0) out[0] = -(C0 + logf((sh.m.pm[0] + sh.m.pm[1]) + (sh.m.pm[2] + sh.m.pm[3])));
    }
}

extern "C" void kernel_launch(void* const* d_in, const int* in_sizes, int n_in,
                              void* d_out, int out_size, void* d_ws, size_t ws_size,
                              hipStream_t stream) {
    const float* X  = (const float*)d_in[0];   // [32768,64]
    const float* mu = (const float*)d_in[1];   // [32,64]
    const float* L  = (const float*)d_in[2];   // [32,64,64]
    const float* w  = (const float*)d_in[3];   // [32]
    // d_in[4] = it (unused)

    char* ws = (char*)d_ws;
    short* Bpack   = (short*)ws;                       // 384 KB
    float* cstC    = (float*)(ws + 32 * 12 * 64 * 8 * 2);
    float* parts   = cstC + KC;                        // 2048 floats
    int*   flags   = (int*)(parts + 2048);             // 32 ints (poison != MAGIC)
    int*   tailctr = flags + KC;

    fused_kernel<<<2048, 256, 0, stream>>>(X, mu, L, w, Bpack, cstC,
                                           parts, flags, tailctr, (float*)d_out);
}

// Round 14
// 159.039 us; speedup vs baseline: 1.2249x; 1.2249x over previous
//
#include <hip/hip_runtime.h>
#include <math.h>

#define DIM 64
#define KC 32
#define NPTS 32768
#define LOG_2PI 1.8378770664093453f
#define C0 (-58.0f)   // fixed logsumexp reference: logp <= -58.81 always
#define ST 68         // prep LDS row stride (words): mult of 4 -> 16B-aligned

typedef __attribute__((ext_vector_type(8))) short short8;
typedef __attribute__((ext_vector_type(4))) float float4v;

__device__ __forceinline__ unsigned short f2bf(float f) {
    unsigned u = __float_as_uint(f);
    u += 0x7FFFu + ((u >> 16) & 1u);   // RNE
    return (unsigned short)(u >> 16);
}

__device__ __forceinline__ float rdlane(float v, int l) {
    return __int_as_float(__builtin_amdgcn_readlane(__float_as_int(v), l));
}

// DPP adds (VALU pipe) — HW-verified correct rounds 7-13.
template <int CTRL>
__device__ __forceinline__ float dpp_add(float x) {
    int t = __builtin_amdgcn_mov_dpp(__float_as_int(x), CTRL, 0xF, 0xF, true);
    return x + __int_as_float(t);
}
__device__ __forceinline__ float sum16(float x) {
    x = dpp_add<0xB1>(x);
    x = dpp_add<0x4E>(x);
    x = dpp_add<0x141>(x);
    x = dpp_add<0x140>(x);
    return x;
}

// ============================================================================
// Prep: r10 structure with 8-COLUMN blocked steps (8 serial steps, was 16).
// Per step: wave0 = 8 shared-crow dots -> 8x8 register micro-factorization
// (28 readlane cross-fixes) -> 2x ds_write_b128 C cols + rdbuf; wave1 = 8
// shared-yrow inverse dots, post-barrier 8-row fix from 10 uniform b128 reads
// of the fresh C block. Junk/zero invariants generalize from blocked-4 (r10):
// rows >= c never receive junk writes, cols >= c are exact zeros pre-step,
// readlanes only ever target lanes >= c. Also zeroes main's tail counter.
// ============================================================================
__global__ __launch_bounds__(256) void prep_kernel(
    const float* __restrict__ L, const float* __restrict__ mu,
    const float* __restrict__ w, short* __restrict__ Bpack,
    float* __restrict__ cstC, int* __restrict__ tailctr)
{
    const int k = blockIdx.x;
    const int t = threadIdx.x;
    const int wv = t >> 6;
    const int ln = t & 63;
    __shared__ float Llds[DIM * ST];
    __shared__ float Sig[DIM * ST];
    __shared__ float Clds[DIM * ST];
    __shared__ float Ylds[DIM * ST];   // Ylds[a*ST + b] = M[b][a]
    __shared__ float qlds[DIM];
    __shared__ float rdbuf[DIM];
    __shared__ float ldet;

    if (k == 0 && t == 0) *tailctr = 0;   // main's folded-final counter

    for (int idx = t; idx < DIM * DIM; idx += 256) {
        int r = idx >> 6, c = idx & 63;
        float v = L[(size_t)k * DIM * DIM + idx];
        Llds[r * ST + c] = (c <= r) ? v : 0.f;
    }
    for (int idx = t; idx < DIM * ST; idx += 256) {
        Clds[idx] = 0.f;
        Ylds[idx] = 0.f;
    }
    __syncthreads();

    // ---- P1: Sigma = I + tril(L)tril(L)^T (4 waves x 16 cols)
    {
        float Lr[DIM];
        const float2* lp = (const float2*)(Llds + ln * ST);
#pragma unroll
        for (int p = 0; p < 32; ++p) {
            float2 v = lp[p];
            Lr[2 * p] = v.x; Lr[2 * p + 1] = v.y;
        }
#pragma unroll 1
        for (int jj = 0; jj < 16; ++jj) {
            const int j = wv * 16 + jj;
            const float2* up = (const float2*)(Llds + j * ST);
            float a0 = 0.f, a1 = 0.f, a2 = 0.f, a3 = 0.f;
#pragma unroll
            for (int p = 0; p < 32; p += 2) {
                float2 u0 = up[p], u1 = up[p + 1];
                a0 = fmaf(Lr[2 * p], u0.x, a0);
                a1 = fmaf(Lr[2 * p + 1], u0.y, a1);
                a2 = fmaf(Lr[2 * p + 2], u1.x, a2);
                a3 = fmaf(Lr[2 * p + 3], u1.y, a3);
            }
            float s = (a0 + a1) + (a2 + a3);
            if (j == ln) s += 1.f;
            Sig[ln * ST + j] = s;
        }
    }
    __syncthreads();

    // ---- P2: 8-col blocked Cholesky + inverse, two waves, 8 steps
    {
        const float2* crow = (const float2*)(Clds + ln * ST);
        const float2* yrow = (const float2*)(Ylds + ln * ST);
        float ld2 = 0.f;
#pragma unroll 1
        for (int c = 0; c < DIM; c += 8) {
            const float2* u0 = (const float2*)(Clds + (c + 0) * ST);
            const float2* u1 = (const float2*)(Clds + (c + 1) * ST);
            const float2* u2 = (const float2*)(Clds + (c + 2) * ST);
            const float2* u3 = (const float2*)(Clds + (c + 3) * ST);
            const float2* u4 = (const float2*)(Clds + (c + 4) * ST);
            const float2* u5 = (const float2*)(Clds + (c + 5) * ST);
            const float2* u6 = (const float2*)(Clds + (c + 6) * ST);
            const float2* u7 = (const float2*)(Clds + (c + 7) * ST);
            float si0 = 0.f, si1 = 0.f, si2 = 0.f, si3 = 0.f;
            float si4 = 0.f, si5 = 0.f, si6 = 0.f, si7 = 0.f;
            if (wv == 0) {
                float d0 = 0.f, d1 = 0.f, d2 = 0.f, d3 = 0.f;
                float d4 = 0.f, d5 = 0.f, d6 = 0.f, d7 = 0.f;
#pragma unroll
                for (int p = 0; p < 32; ++p) {
                    float2 cr = crow[p];
                    float2 a0 = u0[p], a1 = u1[p], a2 = u2[p], a3 = u3[p];
                    float2 a4 = u4[p], a5 = u5[p], a6 = u6[p], a7 = u7[p];
                    d0 = fmaf(cr.x, a0.x, fmaf(cr.y, a0.y, d0));
                    d1 = fmaf(cr.x, a1.x, fmaf(cr.y, a1.y, d1));
                    d2 = fmaf(cr.x, a2.x, fmaf(cr.y, a2.y, d2));
                    d3 = fmaf(cr.x, a3.x, fmaf(cr.y, a3.y, d3));
                    d4 = fmaf(cr.x, a4.x, fmaf(cr.y, a4.y, d4));
                    d5 = fmaf(cr.x, a5.x, fmaf(cr.y, a5.y, d5));
                    d6 = fmaf(cr.x, a6.x, fmaf(cr.y, a6.y, d6));
                    d7 = fmaf(cr.x, a7.x, fmaf(cr.y, a7.y, d7));
                }
                const float4 g0 = *(const float4*)(Sig + ln * ST + c);
                const float4 g1 = *(const float4*)(Sig + ln * ST + c + 4);
                float s0 = g0.x - d0, s1 = g0.y - d1, s2 = g0.z - d2, s3 = g0.w - d3;
                float s4 = g1.x - d4, s5 = g1.y - d5, s6 = g1.z - d6, s7 = g1.w - d7;
                // 8x8 micro-factorization (registers + readlane)
                float dd0 = rdlane(s0, c + 0); float rd0 = __builtin_amdgcn_rsqf(dd0);
                float v0 = s0 * rd0;
                s1 = fmaf(-v0, rdlane(v0, c + 1), s1);
                s2 = fmaf(-v0, rdlane(v0, c + 2), s2);
                s3 = fmaf(-v0, rdlane(v0, c + 3), s3);
                s4 = fmaf(-v0, rdlane(v0, c + 4), s4);
                s5 = fmaf(-v0, rdlane(v0, c + 5), s5);
                s6 = fmaf(-v0, rdlane(v0, c + 6), s6);
                s7 = fmaf(-v0, rdlane(v0, c + 7), s7);
                float dd1 = rdlane(s1, c + 1); float rd1 = __builtin_amdgcn_rsqf(dd1);
                float v1 = s1 * rd1;
                s2 = fmaf(-v1, rdlane(v1, c + 2), s2);
                s3 = fmaf(-v1, rdlane(v1, c + 3), s3);
                s4 = fmaf(-v1, rdlane(v1, c + 4), s4);
                s5 = fmaf(-v1, rdlane(v1, c + 5), s5);
                s6 = fmaf(-v1, rdlane(v1, c + 6), s6);
                s7 = fmaf(-v1, rdlane(v1, c + 7), s7);
                float dd2 = rdlane(s2, c + 2); float rd2 = __builtin_amdgcn_rsqf(dd2);
                float v2 = s2 * rd2;
                s3 = fmaf(-v2, rdlane(v2, c + 3), s3);
                s4 = fmaf(-v2, rdlane(v2, c + 4), s4);
                s5 = fmaf(-v2, rdlane(v2, c + 5), s5);
                s6 = fmaf(-v2, rdlane(v2, c + 6), s6);
                s7 = fmaf(-v2, rdlane(v2, c + 7), s7);
                float dd3 = rdlane(s3, c + 3); float rd3 = __builtin_amdgcn_rsqf(dd3);
                float v3 = s3 * rd3;
                s4 = fmaf(-v3, rdlane(v3, c + 4), s4);
                s5 = fmaf(-v3, rdlane(v3, c + 5), s5);
                s6 = fmaf(-v3, rdlane(v3, c + 6), s6);
                s7 = fmaf(-v3, rdlane(v3, c + 7), s7);
                float dd4 = rdlane(s4, c + 4); float rd4 = __builtin_amdgcn_rsqf(dd4);
                float v4 = s4 * rd4;
                s5 = fmaf(-v4, rdlane(v4, c + 5), s5);
                s6 = fmaf(-v4, rdlane(v4, c + 6), s6);
                s7 = fmaf(-v4, rdlane(v4, c + 7), s7);
                float dd5 = rdlane(s5, c + 5); float rd5 = __builtin_amdgcn_rsqf(dd5);
                float v5 = s5 * rd5;
                s6 = fmaf(-v5, rdlane(v5, c + 6), s6);
                s7 = fmaf(-v5, rdlane(v5, c + 7), s7);
                float dd6 = rdlane(s6, c + 6); float rd6 = __builtin_amdgcn_rsqf(dd6);
                float v6 = s6 * rd6;
                s7 = fmaf(-v6, rdlane(v6, c + 7), s7);
                float dd7 = rdlane(s7, c + 7); float rd7 = __builtin_amdgcn_rsqf(dd7);
                float v7 = s7 * rd7;
                ld2 += ((__logf(dd0) + __logf(dd1)) + (__logf(dd2) + __logf(dd3)))
                     + ((__logf(dd4) + __logf(dd5)) + (__logf(dd6) + __logf(dd7)));
                *(float4*)(Clds + ln * ST + c)     = make_float4(v0, v1, v2, v3);
                *(float4*)(Clds + ln * ST + c + 4) = make_float4(v4, v5, v6, v7);
                if (ln == 0) {
                    *(float4*)(rdbuf + c)     = make_float4(rd0, rd1, rd2, rd3);
                    *(float4*)(rdbuf + c + 4) = make_float4(rd4, rd5, rd6, rd7);
                }
            } else if (wv == 1) {
                float e0 = 0.f, e1 = 0.f, e2 = 0.f, e3 = 0.f;
                float e4 = 0.f, e5 = 0.f, e6 = 0.f, e7 = 0.f;
#pragma unroll
                for (int p = 0; p < 32; ++p) {
                    float2 yr = yrow[p];
                    float2 a0 = u0[p], a1 = u1[p], a2 = u2[p], a3 = u3[p];
                    float2 a4 = u4[p], a5 = u5[p], a6 = u6[p], a7 = u7[p];
                    e0 = fmaf(yr.x, a0.x, fmaf(yr.y, a0.y, e0));
                    e1 = fmaf(yr.x, a1.x, fmaf(yr.y, a1.y, e1));
                    e2 = fmaf(yr.x, a2.x, fmaf(yr.y, a2.y, e2));
                    e3 = fmaf(yr.x, a3.x, fmaf(yr.y, a3.y, e3));
                    e4 = fmaf(yr.x, a4.x, fmaf(yr.y, a4.y, e4));
                    e5 = fmaf(yr.x, a5.x, fmaf(yr.y, a5.y, e5));
                    e6 = fmaf(yr.x, a6.x, fmaf(yr.y, a6.y, e6));
                    e7 = fmaf(yr.x, a7.x, fmaf(yr.y, a7.y, e7));
                }
                si0 = ((ln == c + 0) ? 1.f : 0.f) - e0;
                si1 = ((ln == c + 1) ? 1.f : 0.f) - e1;
                si2 = ((ln == c + 2) ? 1.f : 0.f) - e2;
                si3 = ((ln == c + 3) ? 1.f : 0.f) - e3;
                si4 = ((ln == c + 4) ? 1.f : 0.f) - e4;
                si5 = ((ln == c + 5) ? 1.f : 0.f) - e5;
                si6 = ((ln == c + 6) ? 1.f : 0.f) - e6;
                si7 = ((ln == c + 7) ? 1.f : 0.f) - e7;
            }
            __syncthreads();   // publishes C cols c..c+7 + rdbuf
            if (wv == 1) {
                const float4 ra = *(const float4*)(rdbuf + c);
                const float4 rb = *(const float4*)(rdbuf + c + 4);
                const float4 r1a = *(const float4*)(Clds + (c + 1) * ST + c);
                const float4 r2a = *(const float4*)(Clds + (c + 2) * ST + c);
                const float4 r3a = *(const float4*)(Clds + (c + 3) * ST + c);
                const float4 r4a = *(const float4*)(Clds + (c + 4) * ST + c);
                const float4 r5a = *(const float4*)(Clds + (c + 5) * ST + c);
                const float4 r5b = *(const float4*)(Clds + (c + 5) * ST + c + 4);
                const float4 r6a = *(const float4*)(Clds + (c + 6) * ST + c);
                const float4 r6b = *(const float4*)(Clds + (c + 6) * ST + c + 4);
                const float4 r7a = *(const float4*)(Clds + (c + 7) * ST + c);
                const float4 r7b = *(const float4*)(Clds + (c + 7) * ST + c + 4);
                float y0 = si0 * ra.x;
                float y1 = (si1 - r1a.x * y0) * ra.y;
                float y2 = (si2 - r2a.x * y0 - r2a.y * y1) * ra.z;
                float y3 = (si3 - r3a.x * y0 - r3a.y * y1 - r3a.z * y2) * ra.w;
                float y4 = (si4 - r4a.x * y0 - r4a.y * y1 - r4a.z * y2 - r4a.w * y3) * rb.x;
                float y5 = (si5 - r5a.x * y0 - r5a.y * y1 - r5a.z * y2 - r5a.w * y3
                                - r5b.x * y4) * rb.y;
                float y6 = (si6 - r6a.x * y0 - r6a.y * y1 - r6a.z * y2 - r6a.w * y3
                                - r6b.x * y4 - r6b.y * y5) * rb.z;
                float y7 = (si7 - r7a.x * y0 - r7a.y * y1 - r7a.z * y2 - r7a.w * y3
                                - r7b.x * y4 - r7b.y * y5 - r7b.z * y6) * rb.w;
                float4 ya, yb;
                ya.x = (ln <= c + 0) ? y0 : 0.f;
                ya.y = (ln <= c + 1) ? y1 : 0.f;
                ya.z = (ln <= c + 2) ? y2 : 0.f;
                ya.w = (ln <= c + 3) ? y3 : 0.f;
                yb.x = (ln <= c + 4) ? y4 : 0.f;
                yb.y = (ln <= c + 5) ? y5 : 0.f;
                yb.z = (ln <= c + 6) ? y6 : 0.f;
                yb.w = (ln <= c + 7) ? y7 : 0.f;
                *(float4*)(Ylds + ln * ST + c)     = ya;
                *(float4*)(Ylds + ln * ST + c + 4) = yb;
            }
        }
        if (wv == 0 && ln == 0) ldet = ld2;
    }
    __syncthreads();

    if (wv == 0) {
        const float* muk = mu + k * DIM;
        float qv = 0.f;
#pragma unroll 8
        for (int j = 0; j < DIM; ++j)
            qv = fmaf(Ylds[j * ST + ln], muk[j], qv);
        qlds[ln] = qv;
        if (ln == 0) {
            float wm = -3.0e38f;
            for (int i = 0; i < KC; ++i) wm = fmaxf(wm, w[i]);
            float se = 0.f;
            for (int i = 0; i < KC; ++i) se += __expf(w[i] - wm);
            float logw = w[k] - (wm + __logf(se));
            cstC[k] = -0.5f * (DIM * LOG_2PI + ldet) + logw - C0;
        }
    }
    __syncthreads();

    {
        const int ct = wv;
        const int col = ct * 16 + (ln & 15);
        const int kb = (ln >> 4) * 8;
#pragma unroll
        for (int kt = 0; kt < 3; ++kt) {
            short8 v;
            if (kt < 2) {
#pragma unroll
                for (int e = 0; e < 8; ++e)
                    v[e] = (short)f2bf(Ylds[(kt * 32 + kb + e) * ST + col]);
            } else {
#pragma unroll
                for (int e = 0; e < 8; ++e)
                    v[e] = (short)((kb + e == 0) ? f2bf(-qlds[col]) : 0);
            }
            *(short8*)(Bpack + ((size_t)(k * 12 + ct * 3 + kt) * 64 + ln) * 8) = v;
        }
    }
}

// ============================================================================
// Main: r12 verbatim (LDS-staged B, (256,2), acc-init -q fold, DPP sum16)
// + r7/r11/r13-validated atomic tail reduction (final_kernel folded in).
// ============================================================================
__global__ __launch_bounds__(256, 2) void main_kernel(
    const float* __restrict__ X, const float* __restrict__ Bpack,
    const float* __restrict__ cstC, float* __restrict__ partials,
    int* __restrict__ tailctr, float* __restrict__ out)
{
    const int tid = threadIdx.x;
    const int lane = tid & 63;
    const int wv = tid >> 6;
    const int ks = blockIdx.x & 7;         // k in [4ks, 4ks+4)
    const int g = blockIdx.x >> 3;         // row group: 128 rows
    const int m = lane & 15;

    __shared__ float4 Bsh[3072];           // 48 KB
    __shared__ float pm[4];
    __shared__ int lastdone;
    {
        const float4* Bg = (const float4*)Bpack + (size_t)ks * 3072;
#pragma unroll
        for (int it = 0; it < 12; ++it)
            Bsh[it * 256 + tid] = Bg[it * 256 + tid];
    }

    const int rbase = g * 128 + wv * 32;
    const int jb = (lane >> 4) * 8;
    const float* Xr0 = X + (size_t)(rbase + m) * DIM;
    const float* Xr1 = Xr0 + 16 * DIM;
    short8 a0, a1, b0r, b1r;
#pragma unroll
    for (int e = 0; e < 8; ++e) {
        a0[e] = (short)f2bf(Xr0[jb + e]);
        a1[e] = (short)f2bf(Xr0[32 + jb + e]);
        b0r[e] = (short)f2bf(Xr1[jb + e]);
        b1r[e] = (short)f2bf(Xr1[32 + jb + e]);
    }

    __syncthreads();

    const short8* Bs = (const short8*)Bsh;
    const short* Bss = (const short*)Bsh;
    float acc = 0.f;
#pragma unroll
    for (int kk = 0; kk < 4; ++kk) {
        const int k = ks * 4 + kk;
        float p0 = 0.f, p1 = 0.f, p2 = 0.f, p3 = 0.f;
        float r0 = 0.f, r1 = 0.f, r2 = 0.f, r3 = 0.f;
#pragma unroll
        for (int ct = 0; ct < 4; ++ct) {
            short8 f0 = Bs[(kk * 12 + ct * 3 + 0) * 64 + lane];
            short8 f1 = Bs[(kk * 12 + ct * 3 + 1) * 64 + lane];
            short nqs = Bss[(size_t)((kk * 12 + ct * 3 + 2) * 64 + m) * 8];
            float nq = __int_as_float(((int)(unsigned short)nqs) << 16);
            float4v c0 = {nq, nq, nq, nq};   // -q folded via accumulator init
            c0 = __builtin_amdgcn_mfma_f32_16x16x32_bf16(a0, f0, c0, 0, 0, 0);
            c0 = __builtin_amdgcn_mfma_f32_16x16x32_bf16(a1, f1, c0, 0, 0, 0);
            float4v c1 = {nq, nq, nq, nq};
            c1 = __builtin_amdgcn_mfma_f32_16x16x32_bf16(b0r, f0, c1, 0, 0, 0);
            c1 = __builtin_amdgcn_mfma_f32_16x16x32_bf16(b1r, f1, c1, 0, 0, 0);
            p0 = fmaf(c0[0], c0[0], p0); p1 = fmaf(c0[1], c0[1], p1);
            p2 = fmaf(c0[2], c0[2], p2); p3 = fmaf(c0[3], c0[3], p3);
            r0 = fmaf(c1[0], c1[0], r0); r1 = fmaf(c1[1], c1[1], r1);
            r2 = fmaf(c1[2], c1[2], r2); r3 = fmaf(c1[3], c1[3], r3);
        }
        const float cc = cstC[k];          // wave-uniform s_load
        acc += __expf(fmaf(-0.5f, sum16(p0), cc)) + __expf(fmaf(-0.5f, sum16(p1), cc));
        acc += __expf(fmaf(-0.5f, sum16(p2), cc)) + __expf(fmaf(-0.5f, sum16(p3), cc));
        acc += __expf(fmaf(-0.5f, sum16(r0), cc)) + __expf(fmaf(-0.5f, sum16(r1), cc));
        acc += __expf(fmaf(-0.5f, sum16(r2), cc)) + __expf(fmaf(-0.5f, sum16(r3), cc));
    }
    acc += __shfl_xor(acc, 16, 64);
    acc += __shfl_xor(acc, 32, 64);

    if (lane == 0) pm[wv] = acc;
    __syncthreads();
    if (tid == 0) {
        partials[blockIdx.x] = (pm[0] + pm[1]) + (pm[2] + pm[3]);
        __threadfence();                          // release partials
        lastdone = (atomicAdd(tailctr, 1) == 2047) ? 1 : 0;
    }
    __syncthreads();
    if (lastdone) {                               // block-uniform
        __threadfence();                          // acquire others' partials
        float s = 0.f;
        for (int i = tid; i < 2048; i += 256) s += partials[i];
#pragma unroll
        for (int mm = 1; mm <= 32; mm <<= 1) s += __shfl_xor(s, mm, 64);
        if (lane == 0) pm[wv] = s;
        __syncthreads();
        if (tid == 0) out[0] = -(C0 + logf((pm[0] + pm[1]) + (pm[2] + pm[3])));
    }
}

extern "C" void kernel_launch(void* const* d_in, const int* in_sizes, int n_in,
                              void* d_out, int out_size, void* d_ws, size_t ws_size,
                              hipStream_t stream) {
    const float* X  = (const float*)d_in[0];   // [32768,64]
    const float* mu = (const float*)d_in[1];   // [32,64]
    const float* L  = (const float*)d_in[2];   // [32,64,64]
    const float* w  = (const float*)d_in[3];   // [32]
    // d_in[4] = it (unused)

    char* ws = (char*)d_ws;
    short* Bpack   = (short*)ws;                       // 384 KB
    float* cstC    = (float*)(ws + 32 * 12 * 64 * 8 * 2);
    float* parts   = cstC + KC;                        // 2048 floats
    int*   tailctr = (int*)(parts + 2048);

    prep_kernel<<<KC, 256, 0, stream>>>(L, mu, w, Bpack, cstC, tailctr);
    main_kernel<<<2048, 256, 0, stream>>>(X, (const float*)Bpack, cstC, parts,
                                          tailctr, (float*)d_out);
}

// Round 15
// 114.154 us; speedup vs baseline: 1.7066x; 1.3932x over previous
//
#include <hip/hip_runtime.h>
#include <math.h>

#define DIM 64
#define KC 32
#define NPTS 32768
#define LOG_2PI 1.8378770664093453f
#define C0 (-58.0f)   // fixed logsumexp reference: logp <= -58.81 always
#define ST 68         // prep LDS row stride (words): mult of 4 -> 16B-aligned

typedef __attribute__((ext_vector_type(8))) short short8;
typedef __attribute__((ext_vector_type(4))) float float4v;

__device__ __forceinline__ unsigned short f2bf(float f) {
    unsigned u = __float_as_uint(f);
    u += 0x7FFFu + ((u >> 16) & 1u);   // RNE
    return (unsigned short)(u >> 16);
}

__device__ __forceinline__ float rdlane(float v, int l) {
    return __int_as_float(__builtin_amdgcn_readlane(__float_as_int(v), l));
}

// DPP adds (VALU pipe) — HW-verified correct rounds 7-14.
template <int CTRL>
__device__ __forceinline__ float dpp_add(float x) {
    int t = __builtin_amdgcn_mov_dpp(__float_as_int(x), CTRL, 0xF, 0xF, true);
    return x + __int_as_float(t);
}
__device__ __forceinline__ float sum16(float x) {
    x = dpp_add<0xB1>(x);
    x = dpp_add<0x4E>(x);
    x = dpp_add<0x141>(x);
    x = dpp_add<0x140>(x);
    return x;
}

// ============================================================================
// Prep: 8-column blocked two-wave Cholesky + inverse (8 serial steps) — r14's
// version, which improved prep ~32 -> ~24us. Junk/zero invariants: rows >= c
// never receive junk writes, cols >= c are exact zeros pre-step, readlanes
// only target lanes >= c; zero-init tails make full-row dots exact.
// ============================================================================
__global__ __launch_bounds__(256) void prep_kernel(
    const float* __restrict__ L, const float* __restrict__ mu,
    const float* __restrict__ w, short* __restrict__ Bpack,
    float* __restrict__ cstC)
{
    const int k = blockIdx.x;
    const int t = threadIdx.x;
    const int wv = t >> 6;
    const int ln = t & 63;
    __shared__ float Llds[DIM * ST];
    __shared__ float Sig[DIM * ST];
    __shared__ float Clds[DIM * ST];
    __shared__ float Ylds[DIM * ST];   // Ylds[a*ST + b] = M[b][a]
    __shared__ float qlds[DIM];
    __shared__ float rdbuf[DIM];
    __shared__ float ldet;

    for (int idx = t; idx < DIM * DIM; idx += 256) {
        int r = idx >> 6, c = idx & 63;
        float v = L[(size_t)k * DIM * DIM + idx];
        Llds[r * ST + c] = (c <= r) ? v : 0.f;
    }
    for (int idx = t; idx < DIM * ST; idx += 256) {
        Clds[idx] = 0.f;
        Ylds[idx] = 0.f;
    }
    __syncthreads();

    // ---- P1: Sigma = I + tril(L)tril(L)^T (4 waves x 16 cols)
    {
        float Lr[DIM];
        const float2* lp = (const float2*)(Llds + ln * ST);
#pragma unroll
        for (int p = 0; p < 32; ++p) {
            float2 v = lp[p];
            Lr[2 * p] = v.x; Lr[2 * p + 1] = v.y;
        }
#pragma unroll 1
        for (int jj = 0; jj < 16; ++jj) {
            const int j = wv * 16 + jj;
            const float2* up = (const float2*)(Llds + j * ST);
            float a0 = 0.f, a1 = 0.f, a2 = 0.f, a3 = 0.f;
#pragma unroll
            for (int p = 0; p < 32; p += 2) {
                float2 u0 = up[p], u1 = up[p + 1];
                a0 = fmaf(Lr[2 * p], u0.x, a0);
                a1 = fmaf(Lr[2 * p + 1], u0.y, a1);
                a2 = fmaf(Lr[2 * p + 2], u1.x, a2);
                a3 = fmaf(Lr[2 * p + 3], u1.y, a3);
            }
            float s = (a0 + a1) + (a2 + a3);
            if (j == ln) s += 1.f;
            Sig[ln * ST + j] = s;
        }
    }
    __syncthreads();

    // ---- P2: 8-col blocked Cholesky + inverse, two waves, 8 steps
    {
        const float2* crow = (const float2*)(Clds + ln * ST);
        const float2* yrow = (const float2*)(Ylds + ln * ST);
        float ld2 = 0.f;
#pragma unroll 1
        for (int c = 0; c < DIM; c += 8) {
            const float2* u0 = (const float2*)(Clds + (c + 0) * ST);
            const float2* u1 = (const float2*)(Clds + (c + 1) * ST);
            const float2* u2 = (const float2*)(Clds + (c + 2) * ST);
            const float2* u3 = (const float2*)(Clds + (c + 3) * ST);
            const float2* u4 = (const float2*)(Clds + (c + 4) * ST);
            const float2* u5 = (const float2*)(Clds + (c + 5) * ST);
            const float2* u6 = (const float2*)(Clds + (c + 6) * ST);
            const float2* u7 = (const float2*)(Clds + (c + 7) * ST);
            float si0 = 0.f, si1 = 0.f, si2 = 0.f, si3 = 0.f;
            float si4 = 0.f, si5 = 0.f, si6 = 0.f, si7 = 0.f;
            if (wv == 0) {
                float d0 = 0.f, d1 = 0.f, d2 = 0.f, d3 = 0.f;
                float d4 = 0.f, d5 = 0.f, d6 = 0.f, d7 = 0.f;
#pragma unroll
                for (int p = 0; p < 32; ++p) {
                    float2 cr = crow[p];
                    float2 a0 = u0[p], a1 = u1[p], a2 = u2[p], a3 = u3[p];
                    float2 a4 = u4[p], a5 = u5[p], a6 = u6[p], a7 = u7[p];
                    d0 = fmaf(cr.x, a0.x, fmaf(cr.y, a0.y, d0));
                    d1 = fmaf(cr.x, a1.x, fmaf(cr.y, a1.y, d1));
                    d2 = fmaf(cr.x, a2.x, fmaf(cr.y, a2.y, d2));
                    d3 = fmaf(cr.x, a3.x, fmaf(cr.y, a3.y, d3));
                    d4 = fmaf(cr.x, a4.x, fmaf(cr.y, a4.y, d4));
                    d5 = fmaf(cr.x, a5.x, fmaf(cr.y, a5.y, d5));
                    d6 = fmaf(cr.x, a6.x, fmaf(cr.y, a6.y, d6));
                    d7 = fmaf(cr.x, a7.x, fmaf(cr.y, a7.y, d7));
                }
                const float4 g0 = *(const float4*)(Sig + ln * ST + c);
                const float4 g1 = *(const float4*)(Sig + ln * ST + c + 4);
                float s0 = g0.x - d0, s1 = g0.y - d1, s2 = g0.z - d2, s3 = g0.w - d3;
                float s4 = g1.x - d4, s5 = g1.y - d5, s6 = g1.z - d6, s7 = g1.w - d7;
                float dd0 = rdlane(s0, c + 0); float rd0 = __builtin_amdgcn_rsqf(dd0);
                float v0 = s0 * rd0;
                s1 = fmaf(-v0, rdlane(v0, c + 1), s1);
                s2 = fmaf(-v0, rdlane(v0, c + 2), s2);
                s3 = fmaf(-v0, rdlane(v0, c + 3), s3);
                s4 = fmaf(-v0, rdlane(v0, c + 4), s4);
                s5 = fmaf(-v0, rdlane(v0, c + 5), s5);
                s6 = fmaf(-v0, rdlane(v0, c + 6), s6);
                s7 = fmaf(-v0, rdlane(v0, c + 7), s7);
                float dd1 = rdlane(s1, c + 1); float rd1 = __builtin_amdgcn_rsqf(dd1);
                float v1 = s1 * rd1;
                s2 = fmaf(-v1, rdlane(v1, c + 2), s2);
                s3 = fmaf(-v1, rdlane(v1, c + 3), s3);
                s4 = fmaf(-v1, rdlane(v1, c + 4), s4);
                s5 = fmaf(-v1, rdlane(v1, c + 5), s5);
                s6 = fmaf(-v1, rdlane(v1, c + 6), s6);
                s7 = fmaf(-v1, rdlane(v1, c + 7), s7);
                float dd2 = rdlane(s2, c + 2); float rd2 = __builtin_amdgcn_rsqf(dd2);
                float v2 = s2 * rd2;
                s3 = fmaf(-v2, rdlane(v2, c + 3), s3);
                s4 = fmaf(-v2, rdlane(v2, c + 4), s4);
                s5 = fmaf(-v2, rdlane(v2, c + 5), s5);
                s6 = fmaf(-v2, rdlane(v2, c + 6), s6);
                s7 = fmaf(-v2, rdlane(v2, c + 7), s7);
                float dd3 = rdlane(s3, c + 3); float rd3 = __builtin_amdgcn_rsqf(dd3);
                float v3 = s3 * rd3;
                s4 = fmaf(-v3, rdlane(v3, c + 4), s4);
                s5 = fmaf(-v3, rdlane(v3, c + 5), s5);
                s6 = fmaf(-v3, rdlane(v3, c + 6), s6);
                s7 = fmaf(-v3, rdlane(v3, c + 7), s7);
                float dd4 = rdlane(s4, c + 4); float rd4 = __builtin_amdgcn_rsqf(dd4);
                float v4 = s4 * rd4;
                s5 = fmaf(-v4, rdlane(v4, c + 5), s5);
                s6 = fmaf(-v4, rdlane(v4, c + 6), s6);
                s7 = fmaf(-v4, rdlane(v4, c + 7), s7);
                float dd5 = rdlane(s5, c + 5); float rd5 = __builtin_amdgcn_rsqf(dd5);
                float v5 = s5 * rd5;
                s6 = fmaf(-v5, rdlane(v5, c + 6), s6);
                s7 = fmaf(-v5, rdlane(v5, c + 7), s7);
                float dd6 = rdlane(s6, c + 6); float rd6 = __builtin_amdgcn_rsqf(dd6);
                float v6 = s6 * rd6;
                s7 = fmaf(-v6, rdlane(v6, c + 7), s7);
                float dd7 = rdlane(s7, c + 7); float rd7 = __builtin_amdgcn_rsqf(dd7);
                float v7 = s7 * rd7;
                ld2 += ((__logf(dd0) + __logf(dd1)) + (__logf(dd2) + __logf(dd3)))
                     + ((__logf(dd4) + __logf(dd5)) + (__logf(dd6) + __logf(dd7)));
                *(float4*)(Clds + ln * ST + c)     = make_float4(v0, v1, v2, v3);
                *(float4*)(Clds + ln * ST + c + 4) = make_float4(v4, v5, v6, v7);
                if (ln == 0) {
                    *(float4*)(rdbuf + c)     = make_float4(rd0, rd1, rd2, rd3);
                    *(float4*)(rdbuf + c + 4) = make_float4(rd4, rd5, rd6, rd7);
                }
            } else if (wv == 1) {
                float e0 = 0.f, e1 = 0.f, e2 = 0.f, e3 = 0.f;
                float e4 = 0.f, e5 = 0.f, e6 = 0.f, e7 = 0.f;
#pragma unroll
                for (int p = 0; p < 32; ++p) {
                    float2 yr = yrow[p];
                    float2 a0 = u0[p], a1 = u1[p], a2 = u2[p], a3 = u3[p];
                    float2 a4 = u4[p], a5 = u5[p], a6 = u6[p], a7 = u7[p];
                    e0 = fmaf(yr.x, a0.x, fmaf(yr.y, a0.y, e0));
                    e1 = fmaf(yr.x, a1.x, fmaf(yr.y, a1.y, e1));
                    e2 = fmaf(yr.x, a2.x, fmaf(yr.y, a2.y, e2));
                    e3 = fmaf(yr.x, a3.x, fmaf(yr.y, a3.y, e3));
                    e4 = fmaf(yr.x, a4.x, fmaf(yr.y, a4.y, e4));
                    e5 = fmaf(yr.x, a5.x, fmaf(yr.y, a5.y, e5));
                    e6 = fmaf(yr.x, a6.x, fmaf(yr.y, a6.y, e6));
                    e7 = fmaf(yr.x, a7.x, fmaf(yr.y, a7.y, e7));
                }
                si0 = ((ln == c + 0) ? 1.f : 0.f) - e0;
                si1 = ((ln == c + 1) ? 1.f : 0.f) - e1;
                si2 = ((ln == c + 2) ? 1.f : 0.f) - e2;
                si3 = ((ln == c + 3) ? 1.f : 0.f) - e3;
                si4 = ((ln == c + 4) ? 1.f : 0.f) - e4;
                si5 = ((ln == c + 5) ? 1.f : 0.f) - e5;
                si6 = ((ln == c + 6) ? 1.f : 0.f) - e6;
                si7 = ((ln == c + 7) ? 1.f : 0.f) - e7;
            }
            __syncthreads();   // publishes C cols c..c+7 + rdbuf
            if (wv == 1) {
                const float4 ra = *(const float4*)(rdbuf + c);
                const float4 rb = *(const float4*)(rdbuf + c + 4);
                const float4 r1a = *(const float4*)(Clds + (c + 1) * ST + c);
                const float4 r2a = *(const float4*)(Clds + (c + 2) * ST + c);
                const float4 r3a = *(const float4*)(Clds + (c + 3) * ST + c);
                const float4 r4a = *(const float4*)(Clds + (c + 4) * ST + c);
                const float4 r5a = *(const float4*)(Clds + (c + 5) * ST + c);
                const float4 r5b = *(const float4*)(Clds + (c + 5) * ST + c + 4);
                const float4 r6a = *(const float4*)(Clds + (c + 6) * ST + c);
                const float4 r6b = *(const float4*)(Clds + (c + 6) * ST + c + 4);
                const float4 r7a = *(const float4*)(Clds + (c + 7) * ST + c);
                const float4 r7b = *(const float4*)(Clds + (c + 7) * ST + c + 4);
                float y0 = si0 * ra.x;
                float y1 = (si1 - r1a.x * y0) * ra.y;
                float y2 = (si2 - r2a.x * y0 - r2a.y * y1) * ra.z;
                float y3 = (si3 - r3a.x * y0 - r3a.y * y1 - r3a.z * y2) * ra.w;
                float y4 = (si4 - r4a.x * y0 - r4a.y * y1 - r4a.z * y2 - r4a.w * y3) * rb.x;
                float y5 = (si5 - r5a.x * y0 - r5a.y * y1 - r5a.z * y2 - r5a.w * y3
                                - r5b.x * y4) * rb.y;
                float y6 = (si6 - r6a.x * y0 - r6a.y * y1 - r6a.z * y2 - r6a.w * y3
                                - r6b.x * y4 - r6b.y * y5) * rb.z;
                float y7 = (si7 - r7a.x * y0 - r7a.y * y1 - r7a.z * y2 - r7a.w * y3
                                - r7b.x * y4 - r7b.y * y5 - r7b.z * y6) * rb.w;
                float4 ya, yb;
                ya.x = (ln <= c + 0) ? y0 : 0.f;
                ya.y = (ln <= c + 1) ? y1 : 0.f;
                ya.z = (ln <= c + 2) ? y2 : 0.f;
                ya.w = (ln <= c + 3) ? y3 : 0.f;
                yb.x = (ln <= c + 4) ? y4 : 0.f;
                yb.y = (ln <= c + 5) ? y5 : 0.f;
                yb.z = (ln <= c + 6) ? y6 : 0.f;
                yb.w = (ln <= c + 7) ? y7 : 0.f;
                *(float4*)(Ylds + ln * ST + c)     = ya;
                *(float4*)(Ylds + ln * ST + c + 4) = yb;
            }
        }
        if (wv == 0 && ln == 0) ldet = ld2;
    }
    __syncthreads();

    if (wv == 0) {
        const float* muk = mu + k * DIM;
        float qv = 0.f;
#pragma unroll 8
        for (int j = 0; j < DIM; ++j)
            qv = fmaf(Ylds[j * ST + ln], muk[j], qv);
        qlds[ln] = qv;
        if (ln == 0) {
            float wm = -3.0e38f;
            for (int i = 0; i < KC; ++i) wm = fmaxf(wm, w[i]);
            float se = 0.f;
            for (int i = 0; i < KC; ++i) se += __expf(w[i] - wm);
            float logw = w[k] - (wm + __logf(se));
            cstC[k] = -0.5f * (DIM * LOG_2PI + ldet) + logw - C0;
        }
    }
    __syncthreads();

    {
        const int ct = wv;
        const int col = ct * 16 + (ln & 15);
        const int kb = (ln >> 4) * 8;
#pragma unroll
        for (int kt = 0; kt < 3; ++kt) {
            short8 v;
            if (kt < 2) {
#pragma unroll
                for (int e = 0; e < 8; ++e)
                    v[e] = (short)f2bf(Ylds[(kt * 32 + kb + e) * ST + col]);
            } else {
#pragma unroll
                for (int e = 0; e < 8; ++e)
                    v[e] = (short)((kb + e == 0) ? f2bf(-qlds[col]) : 0);
            }
            *(short8*)(Bpack + ((size_t)(k * 12 + ct * 3 + kt) * 64 + ln) * 8) = v;
        }
    }
}

// ============================================================================
// Main: r12 verbatim — LDS-staged B, (256,2), acc-init -q fold, DPP sum16,
// block partial write. NO atomic tail: cross-XCD same-line atomics from 2048
// blocks serialize at ~25-30ns each (~55us) — measured r7/r11/r13/r14.
// ============================================================================
__global__ __launch_bounds__(256, 2) void main_kernel(
    const float* __restrict__ X, const float* __restrict__ Bpack,
    const float* __restrict__ cstC, float* __restrict__ partials)
{
    const int tid = threadIdx.x;
    const int lane = tid & 63;
    const int wv = tid >> 6;
    const int ks = blockIdx.x & 7;         // k in [4ks, 4ks+4)
    const int g = blockIdx.x >> 3;         // row group: 128 rows
    const int m = lane & 15;

    __shared__ float4 Bsh[3072];           // 48 KB
    {
        const float4* Bg = (const float4*)Bpack + (size_t)ks * 3072;
#pragma unroll
        for (int it = 0; it < 12; ++it)
            Bsh[it * 256 + tid] = Bg[it * 256 + tid];
    }

    const int rbase = g * 128 + wv * 32;
    const int jb = (lane >> 4) * 8;
    const float* Xr0 = X + (size_t)(rbase + m) * DIM;
    const float* Xr1 = Xr0 + 16 * DIM;
    short8 a0, a1, b0r, b1r;
#pragma unroll
    for (int e = 0; e < 8; ++e) {
        a0[e] = (short)f2bf(Xr0[jb + e]);
        a1[e] = (short)f2bf(Xr0[32 + jb + e]);
        b0r[e] = (short)f2bf(Xr1[jb + e]);
        b1r[e] = (short)f2bf(Xr1[32 + jb + e]);
    }

    __syncthreads();

    const short8* Bs = (const short8*)Bsh;
    const short* Bss = (const short*)Bsh;
    float acc = 0.f;
#pragma unroll
    for (int kk = 0; kk < 4; ++kk) {
        const int k = ks * 4 + kk;
        float p0 = 0.f, p1 = 0.f, p2 = 0.f, p3 = 0.f;
        float r0 = 0.f, r1 = 0.f, r2 = 0.f, r3 = 0.f;
#pragma unroll
        for (int ct = 0; ct < 4; ++ct) {
            short8 f0 = Bs[(kk * 12 + ct * 3 + 0) * 64 + lane];
            short8 f1 = Bs[(kk * 12 + ct * 3 + 1) * 64 + lane];
            short nqs = Bss[(size_t)((kk * 12 + ct * 3 + 2) * 64 + m) * 8];
            float nq = __int_as_float(((int)(unsigned short)nqs) << 16);
            float4v c0 = {nq, nq, nq, nq};   // -q folded via accumulator init
            c0 = __builtin_amdgcn_mfma_f32_16x16x32_bf16(a0, f0, c0, 0, 0, 0);
            c0 = __builtin_amdgcn_mfma_f32_16x16x32_bf16(a1, f1, c0, 0, 0, 0);
            float4v c1 = {nq, nq, nq, nq};
            c1 = __builtin_amdgcn_mfma_f32_16x16x32_bf16(b0r, f0, c1, 0, 0, 0);
            c1 = __builtin_amdgcn_mfma_f32_16x16x32_bf16(b1r, f1, c1, 0, 0, 0);
            p0 = fmaf(c0[0], c0[0], p0); p1 = fmaf(c0[1], c0[1], p1);
            p2 = fmaf(c0[2], c0[2], p2); p3 = fmaf(c0[3], c0[3], p3);
            r0 = fmaf(c1[0], c1[0], r0); r1 = fmaf(c1[1], c1[1], r1);
            r2 = fmaf(c1[2], c1[2], r2); r3 = fmaf(c1[3], c1[3], r3);
        }
        const float cc = cstC[k];          // wave-uniform s_load
        acc += __expf(fmaf(-0.5f, sum16(p0), cc)) + __expf(fmaf(-0.5f, sum16(p1), cc));
        acc += __expf(fmaf(-0.5f, sum16(p2), cc)) + __expf(fmaf(-0.5f, sum16(p3), cc));
        acc += __expf(fmaf(-0.5f, sum16(r0), cc)) + __expf(fmaf(-0.5f, sum16(r1), cc));
        acc += __expf(fmaf(-0.5f, sum16(r2), cc)) + __expf(fmaf(-0.5f, sum16(r3), cc));
    }
    acc += __shfl_xor(acc, 16, 64);
    acc += __shfl_xor(acc, 32, 64);

    __shared__ float pm[4];
    if (lane == 0) pm[wv] = acc;
    __syncthreads();
    if (tid == 0)
        partials[blockIdx.x] = (pm[0] + pm[1]) + (pm[2] + pm[3]);
}

// ============================================================================
// Final: sum 2048 partials -> out = -(C0 + log(S))  (~2us; beats the ~55us
// cross-XCD atomic tail by 25x)
// ============================================================================
__global__ __launch_bounds__(256) void final_kernel(
    const float* __restrict__ partials, int n, float* __restrict__ out)
{
    const int tid = threadIdx.x;
    float s = 0.f;
    for (int i = tid; i < n; i += 256) s += partials[i];
#pragma unroll
    for (int mm = 1; mm <= 32; mm <<= 1) s += __shfl_xor(s, mm, 64);
    __shared__ float pm[4];
    if ((tid & 63) == 0) pm[tid >> 6] = s;
    __syncthreads();
    if (tid == 0) out[0] = -(C0 + logf((pm[0] + pm[1]) + (pm[2] + pm[3])));
}

extern "C" void kernel_launch(void* const* d_in, const int* in_sizes, int n_in,
                              void* d_out, int out_size, void* d_ws, size_t ws_size,
                              hipStream_t stream) {
    const float* X  = (const float*)d_in[0];   // [32768,64]
    const float* mu = (const float*)d_in[1];   // [32,64]
    const float* L  = (const float*)d_in[2];   // [32,64,64]
    const float* w  = (const float*)d_in[3];   // [32]
    // d_in[4] = it (unused)

    char* ws = (char*)d_ws;
    short* Bpack = (short*)ws;                         // 384 KB
    float* cstC  = (float*)(ws + 32 * 12 * 64 * 8 * 2);
    float* parts = cstC + KC;                          // 2048 floats

    prep_kernel<<<KC, 256, 0, stream>>>(L, mu, w, Bpack, cstC);
    main_kernel<<<2048, 256, 0, stream>>>(X, (const float*)Bpack, cstC, parts);
    final_kernel<<<1, 256, 0, stream>>>(parts, 2048, (float*)d_out);
}